// Round 16
// baseline (321.065 us; speedup 1.0000x reference)
//
#include <hip/hip_runtime.h>
#include <hip/hip_bf16.h>

#define N_NODES 16384
#define KDIM    16384
#define HID     64
#define N_EDGES 524288
#define BK      64
#define CAP     80
#define NSLOTS  (N_NODES * CAP)

typedef __bf16 bf16x8 __attribute__((ext_vector_type(8)));
typedef float  f32x4  __attribute__((ext_vector_type(4)));
typedef unsigned uint32x4 __attribute__((ext_vector_type(4)));
typedef __attribute__((address_space(3))) const unsigned* lds_cptr_t;

__device__ __forceinline__ unsigned cvt_pk(float a, float b) {
    unsigned r;
    asm("v_cvt_pk_bf16_f32 %0, %1, %2" : "=v"(r) : "v"(a), "v"(b));
    return r;
}

__device__ __forceinline__ void gload16(const void* g, void* l) {
    __builtin_amdgcn_global_load_lds(
        (const __attribute__((address_space(1))) unsigned*)g,
        (__attribute__((address_space(3))) unsigned*)l,
        16, 0, 0);
}

__device__ __forceinline__ uint32x4 ds_read128(lds_cptr_t p) {
    uint32x4 r;
    asm volatile("ds_read_b128 %0, %1" : "=v"(r) : "v"(p));
    return r;
}

// ---- W1 [K][64] f32  ->  W1t packed [64][K/2] u32 (2 bf16 per u32, pair = (2k, 2k+1))
__global__ void pack_w1t(const float* __restrict__ W1, unsigned* __restrict__ W1t) {
    int tid = blockIdx.x * 256 + threadIdx.x;
    int c  = tid & 63;
    int kp = tid >> 6;
    float f0 = W1[(size_t)(2 * kp)     * HID + c];
    float f1 = W1[(size_t)(2 * kp + 1) * HID + c];
    W1t[(size_t)c * (KDIM / 2) + kp] = cvt_pk(f0, f1);
}

// ---- fused: degree accumulation + (sidx, raw w) pair scatter (one edge pass)
__global__ void deg_scat_k(const int* __restrict__ ei, const float* __restrict__ w,
                           float* deg, int* ptr, int2* __restrict__ slots2) {
    int e = blockIdx.x * 256 + threadIdx.x;
    int d = ei[N_EDGES + e];
    float we = w[e];
    atomicAdd(&deg[d], we);
    int pos = atomicAdd(&ptr[d], 1);
    if (pos < CAP) slots2[d * CAP + pos] = make_int2(ei[e], __float_as_int(we));
}

// ---- hpre = x @ W1 : measured R10 ~193-195 us = 5.6 TB/s (88% of achievable).
__global__ __launch_bounds__(256, 3) void gemm1(const float* __restrict__ x,
                                                const unsigned* __restrict__ w1t,
                                                float* __restrict__ hpre) {
    __shared__ unsigned As_u[2][64 * 64];
    __shared__ unsigned Bs_u[2][64 * 32];

    const int t    = threadIdx.x;
    const int wave = t >> 6;
    const int lane = t & 63;
    const int row0 = blockIdx.x * 64;
    const int y    = blockIdx.y;
    const int k00  = y * 5504;
    const int NTb  = (y < 2) ? 86 : 84;
    const int fr_lo = lane & 15, fr_hi = lane >> 4;
    const int ar    = wave * 16 + fr_lo;

    const float* pA[4];
    #pragma unroll
    for (int i = 0; i < 4; ++i) {
        int row = (wave * 4 + i) * 4 + (lane >> 4);
        int col = ((lane & 15) ^ (row & 15)) * 4;
        pA[i] = x + (size_t)(row0 + row) * KDIM + k00 + col;
    }
    const unsigned* pB[2];
    #pragma unroll
    for (int i = 0; i < 2; ++i) {
        int c = (wave * 2 + i) * 8 + (lane >> 3);
        int s = ((lane & 7) ^ (c & 7)) * 4;
        pB[i] = w1t + (size_t)c * (KDIM / 2) + (k00 >> 1) + s;
    }

    f32x4 acc[4] = {{0.f,0.f,0.f,0.f},{0.f,0.f,0.f,0.f},{0.f,0.f,0.f,0.f},{0.f,0.f,0.f,0.f}};

#define ISSUE(buf) do {                                                          \
    _Pragma("unroll") for (int i = 0; i < 4; ++i)                                \
        gload16(pA[i], &As_u[buf][(wave * 4 + i) * 256]);                        \
    _Pragma("unroll") for (int i = 0; i < 2; ++i)                                \
        gload16(pB[i], &Bs_u[buf][(wave * 2 + i) * 256]);                        \
    _Pragma("unroll") for (int i = 0; i < 4; ++i) pA[i] += BK;                   \
    _Pragma("unroll") for (int i = 0; i < 2; ++i) pB[i] += BK / 2;               \
    } while (0)

    ISSUE(0);

    #pragma unroll 1
    for (int tt = 0; tt < NTb; ++tt) {
        const int buf = tt & 1;
        if (tt + 1 < NTb) {
            ISSUE(buf ^ 1);
            asm volatile("s_waitcnt vmcnt(6)" ::: "memory");
        } else {
            asm volatile("s_waitcnt vmcnt(0)" ::: "memory");
        }
        __builtin_amdgcn_s_barrier();

        const lds_cptr_t Ab = (lds_cptr_t)&As_u[buf][0];
        const lds_cptr_t Bb = (lds_cptr_t)&Bs_u[buf][0];
        uint32x4 av0[2], av1[2], bv[2][4];
        #pragma unroll
        for (int kk = 0; kk < 2; ++kk) {
            int s0 = (kk * 8 + fr_hi * 2) ^ fr_lo;
            av0[kk] = ds_read128(Ab + ar * 64 + s0 * 4);
            av1[kk] = ds_read128(Ab + ar * 64 + (s0 ^ 1) * 4);
            #pragma unroll
            for (int ct = 0; ct < 4; ++ct) {
                int bc = ct * 16 + fr_lo;
                bv[kk][ct] = ds_read128(Bb + bc * 32 + (((kk * 4 + fr_hi) ^ (fr_lo & 7)) << 2));
            }
        }
        asm volatile("s_waitcnt lgkmcnt(0)" ::: "memory");
        __builtin_amdgcn_sched_barrier(0);

        #pragma unroll
        for (int kk = 0; kk < 2; ++kk) {
            f32x4 v0 = __builtin_bit_cast(f32x4, av0[kk]);
            f32x4 v1 = __builtin_bit_cast(f32x4, av1[kk]);
            uint32x4 au = { cvt_pk(v0[0], v0[1]), cvt_pk(v0[2], v0[3]),
                            cvt_pk(v1[0], v1[1]), cvt_pk(v1[2], v1[3]) };
            bf16x8 a = __builtin_bit_cast(bf16x8, au);
            #pragma unroll
            for (int ct = 0; ct < 4; ++ct) {
                bf16x8 b = __builtin_bit_cast(bf16x8, bv[kk][ct]);
                acc[ct] = __builtin_amdgcn_mfma_f32_16x16x32_bf16(a, b, acc[ct], 0, 0, 0);
            }
        }
        __builtin_amdgcn_s_barrier();
    }
#undef ISSUE

    #pragma unroll
    for (int ct = 0; ct < 4; ++ct) {
        int c = ct * 16 + fr_lo;
        #pragma unroll
        for (int r = 0; r < 4; ++r) {
            int row = wave * 16 + fr_hi * 4 + r;
            atomicAdd(&hpre[(size_t)(row0 + row) * HID + c], acc[ct][r]);
        }
    }
}

// ---- layer-1 aggregation: wave = 4 edge-groups x 16 lanes (4 cols each).
__global__ __launch_bounds__(256) void aggfin1_k(
        const int2* __restrict__ slots2, const int* __restrict__ ptr,
        const float* __restrict__ deg, const float* __restrict__ hpre,
        const float* __restrict__ b1, const float* __restrict__ W2,
        float* __restrict__ s_out) {
    int wave = threadIdx.x >> 6;
    int lane = threadIdx.x & 63;
    int dst  = blockIdx.x * 4 + wave;
    int g    = lane >> 4;
    int l    = lane & 15;
    int n    = min(ptr[dst], CAP);
    int base = dst * CAP;
    float dd = rsqrtf(deg[dst] + 1.0f);

    f32x4 acc = {0.f, 0.f, 0.f, 0.f};
    for (int j = g; j < n; j += 4) {
        int2 pr  = slots2[base + j];
        float wn = rsqrtf(deg[pr.x] + 1.0f) * __int_as_float(pr.y) * dd;
        f32x4 h  = *(const f32x4*)&hpre[(size_t)pr.x * HID + l * 4];
        acc += wn * h;
    }
    #pragma unroll
    for (int c = 0; c < 4; ++c) {
        acc[c] += __shfl_xor(acc[c], 16);
        acc[c] += __shfl_xor(acc[c], 32);
    }
    f32x4 hself = *(const f32x4*)&hpre[(size_t)dst * HID + l * 4];
    f32x4 bb    = *(const f32x4*)&b1[l * 4];
    f32x4 ww    = *(const f32x4*)&W2[l * 4];
    float tv = 0.f;
    #pragma unroll
    for (int c = 0; c < 4; ++c) {
        float v = fmaxf(acc[c] + dd * dd * hself[c] + bb[c], 0.f);
        tv += v * ww[c];
    }
    #pragma unroll
    for (int off = 1; off < 16; off <<= 1) tv += __shfl_xor(tv, off);
    if (lane == 0) s_out[dst] = tv;
}

// ---- layer-2 aggregation: one wave per dst, lanes parallel, wn on the fly.
__global__ __launch_bounds__(256) void agg2fin2_k(
        const int2* __restrict__ slots2, const int* __restrict__ ptr,
        const float* __restrict__ deg, const float* __restrict__ s,
        const float* __restrict__ b2, float* __restrict__ out) {
    int wave = threadIdx.x >> 6;
    int lane = threadIdx.x & 63;
    int dst  = blockIdx.x * 4 + wave;
    int n    = min(ptr[dst], CAP);
    float dd = rsqrtf(deg[dst] + 1.0f);
    float acc = 0.f;
    for (int j = lane; j < n; j += 64) {
        int2 pr = slots2[dst * CAP + j];
        acc += rsqrtf(deg[pr.x] + 1.0f) * __int_as_float(pr.y) * dd * s[pr.x];
    }
    #pragma unroll
    for (int off = 32; off > 0; off >>= 1) acc += __shfl_xor(acc, off);
    if (lane == 0) out[dst] = acc + dd * dd * s[dst] + b2[0];
}

extern "C" void kernel_launch(void* const* d_in, const int* in_sizes, int n_in,
                              void* d_out, int out_size, void* d_ws, size_t ws_size,
                              hipStream_t stream) {
    const float* x  = (const float*)d_in[0];
    const int*   ei = (const int*)d_in[1];      // int32 (harness delivers integers as int)
    const float* ew = (const float*)d_in[2];
    const float* W1 = (const float*)d_in[3];
    const float* b1 = (const float*)d_in[4];
    const float* W2 = (const float*)d_in[5];
    const float* b2 = (const float*)d_in[6];
    float* out = (float*)d_out;

    char* ws = (char*)d_ws;
    unsigned* w1t   = (unsigned*)(ws);                             // 2 MiB
    float*    hpre  = (float*)(ws + (2u << 20));                   // 4 MiB [zeroed]
    int*      ptr   = (int*)  (ws + (6u << 20));                   // 64 KiB [zeroed]
    float*    deg   = (float*)(ws + (6u << 20) + (64u << 10));     // 64 KiB [zeroed]
    float*    s     = (float*)(ws + (6u << 20) + (128u << 10));    // 64 KiB
    int2*     slots2= (int2*) (ws + (7u << 20));                   // 10.5 MiB

    // zero hpre + ptr + deg (contiguous)
    hipMemsetAsync(ws + (2u << 20), 0, (4u << 20) + (128u << 10), stream);

    pack_w1t<<<(64 * (KDIM / 2)) / 256, 256, 0, stream>>>(W1, w1t);
    deg_scat_k<<<N_EDGES / 256, 256, 0, stream>>>(ei, ew, deg, ptr, slots2);
    gemm1<<<dim3(N_NODES / 64, 3), 256, 0, stream>>>(x, w1t, hpre);
    // MEASUREMENT: both aggregation kernels are pure functions of their inputs
    // (no accumulation into read buffers), so double-launch is output-identical.
    // dur_us - 295.5 = t(aggfin1) + t(agg2fin2).
    aggfin1_k<<<N_NODES / 4, 256, 0, stream>>>(slots2, ptr, deg, hpre, b1, W2, s);
    aggfin1_k<<<N_NODES / 4, 256, 0, stream>>>(slots2, ptr, deg, hpre, b1, W2, s);
    agg2fin2_k<<<N_NODES / 4, 256, 0, stream>>>(slots2, ptr, deg, s, b2, out);
    agg2fin2_k<<<N_NODES / 4, 256, 0, stream>>>(slots2, ptr, deg, s, b2, out);
}

// Round 17
// 299.454 us; speedup vs baseline: 1.0722x; 1.0722x over previous
//
#include <hip/hip_runtime.h>
#include <hip/hip_bf16.h>

#define N_NODES 16384
#define KDIM    16384
#define HID     64
#define N_EDGES 524288
#define BK      64
#define CAP     80
#define EPB     683   /* ceil(524288 / 768) edges per gemm block */

typedef __bf16 bf16x8 __attribute__((ext_vector_type(8)));
typedef float  f32x4  __attribute__((ext_vector_type(4)));
typedef unsigned uint32x4 __attribute__((ext_vector_type(4)));
typedef __attribute__((address_space(3))) const unsigned* lds_cptr_t;

__device__ __forceinline__ unsigned cvt_pk(float a, float b) {
    unsigned r;
    asm("v_cvt_pk_bf16_f32 %0, %1, %2" : "=v"(r) : "v"(a), "v"(b));
    return r;
}

__device__ __forceinline__ void gload16(const void* g, void* l) {
    __builtin_amdgcn_global_load_lds(
        (const __attribute__((address_space(1))) unsigned*)g,
        (__attribute__((address_space(3))) unsigned*)l,
        16, 0, 0);
}

__device__ __forceinline__ uint32x4 ds_read128(lds_cptr_t p) {
    uint32x4 r;
    asm volatile("ds_read_b128 %0, %1" : "=v"(r) : "v"(p));
    return r;
}

// ---- W1 [K][64] f32  ->  W1t packed [64][K/2] u32 (2 bf16 per u32, pair = (2k, 2k+1))
__global__ void pack_w1t(const float* __restrict__ W1, unsigned* __restrict__ W1t) {
    int tid = blockIdx.x * 256 + threadIdx.x;
    int c  = tid & 63;
    int kp = tid >> 6;
    float f0 = W1[(size_t)(2 * kp)     * HID + c];
    float f1 = W1[(size_t)(2 * kp + 1) * HID + c];
    W1t[(size_t)c * (KDIM / 2) + kp] = cvt_pk(f0, f1);
}

// ---- hpre = x @ W1 (R10-measured ~194 us, 5.6 TB/s = 88% achievable) with the
// deg/CSR edge scatter FOLDED IN: each block fires its ~683-edge slice's
// atomics right after the prologue prefetch — latency hides under the gemm's
// HBM stalls (intra-block overlap; R15's leading-subgrid merge serialized).
__global__ __launch_bounds__(256, 3) void gemm_deg_k(
        const float* __restrict__ x, const unsigned* __restrict__ w1t,
        float* __restrict__ hpre,
        const int* __restrict__ ei, const float* __restrict__ ew,
        float* deg, int* ptr, int2* __restrict__ slots2) {
    __shared__ unsigned As_u[2][64 * 64];
    __shared__ unsigned Bs_u[2][64 * 32];

    const int t    = threadIdx.x;
    const int wave = t >> 6;
    const int lane = t & 63;
    const int row0 = blockIdx.x * 64;
    const int y    = blockIdx.y;
    const int k00  = y * 5504;
    const int NTb  = (y < 2) ? 86 : 84;
    const int fr_lo = lane & 15, fr_hi = lane >> 4;
    const int ar    = wave * 16 + fr_lo;

    const float* pA[4];
    #pragma unroll
    for (int i = 0; i < 4; ++i) {
        int row = (wave * 4 + i) * 4 + (lane >> 4);
        int col = ((lane & 15) ^ (row & 15)) * 4;
        pA[i] = x + (size_t)(row0 + row) * KDIM + k00 + col;
    }
    const unsigned* pB[2];
    #pragma unroll
    for (int i = 0; i < 2; ++i) {
        int c = (wave * 2 + i) * 8 + (lane >> 3);
        int s = ((lane & 7) ^ (c & 7)) * 4;
        pB[i] = w1t + (size_t)c * (KDIM / 2) + (k00 >> 1) + s;
    }

    f32x4 acc[4] = {{0.f,0.f,0.f,0.f},{0.f,0.f,0.f,0.f},{0.f,0.f,0.f,0.f},{0.f,0.f,0.f,0.f}};

#define ISSUE(buf) do {                                                          \
    _Pragma("unroll") for (int i = 0; i < 4; ++i)                                \
        gload16(pA[i], &As_u[buf][(wave * 4 + i) * 256]);                        \
    _Pragma("unroll") for (int i = 0; i < 2; ++i)                                \
        gload16(pB[i], &Bs_u[buf][(wave * 2 + i) * 256]);                        \
    _Pragma("unroll") for (int i = 0; i < 4; ++i) pA[i] += BK;                   \
    _Pragma("unroll") for (int i = 0; i < 2; ++i) pB[i] += BK / 2;               \
    } while (0)

    ISSUE(0);

    // integrated deg accumulation + CSR pair scatter (fire-and-forget; the
    // K-loop's first vmcnt(6) pays a one-time drain of these ops per block)
    {
        int bid   = y * 256 + blockIdx.x;
        int ebase = bid * EPB;
        int eend  = min(ebase + EPB, N_EDGES);
        for (int e = ebase + t; e < eend; e += 256) {
            int d    = ei[N_EDGES + e];
            float we = ew[e];
            atomicAdd(&deg[d], we);
            int pos = atomicAdd(&ptr[d], 1);
            if (pos < CAP) slots2[d * CAP + pos] = make_int2(ei[e], __float_as_int(we));
        }
    }

    #pragma unroll 1
    for (int tt = 0; tt < NTb; ++tt) {
        const int buf = tt & 1;
        if (tt + 1 < NTb) {
            ISSUE(buf ^ 1);
            asm volatile("s_waitcnt vmcnt(6)" ::: "memory");
        } else {
            asm volatile("s_waitcnt vmcnt(0)" ::: "memory");
        }
        __builtin_amdgcn_s_barrier();

        const lds_cptr_t Ab = (lds_cptr_t)&As_u[buf][0];
        const lds_cptr_t Bb = (lds_cptr_t)&Bs_u[buf][0];
        uint32x4 av0[2], av1[2], bv[2][4];
        #pragma unroll
        for (int kk = 0; kk < 2; ++kk) {
            int s0 = (kk * 8 + fr_hi * 2) ^ fr_lo;
            av0[kk] = ds_read128(Ab + ar * 64 + s0 * 4);
            av1[kk] = ds_read128(Ab + ar * 64 + (s0 ^ 1) * 4);
            #pragma unroll
            for (int ct = 0; ct < 4; ++ct) {
                int bc = ct * 16 + fr_lo;
                bv[kk][ct] = ds_read128(Bb + bc * 32 + (((kk * 4 + fr_hi) ^ (fr_lo & 7)) << 2));
            }
        }
        asm volatile("s_waitcnt lgkmcnt(0)" ::: "memory");
        __builtin_amdgcn_sched_barrier(0);

        #pragma unroll
        for (int kk = 0; kk < 2; ++kk) {
            f32x4 v0 = __builtin_bit_cast(f32x4, av0[kk]);
            f32x4 v1 = __builtin_bit_cast(f32x4, av1[kk]);
            uint32x4 au = { cvt_pk(v0[0], v0[1]), cvt_pk(v0[2], v0[3]),
                            cvt_pk(v1[0], v1[1]), cvt_pk(v1[2], v1[3]) };
            bf16x8 a = __builtin_bit_cast(bf16x8, au);
            #pragma unroll
            for (int ct = 0; ct < 4; ++ct) {
                bf16x8 b = __builtin_bit_cast(bf16x8, bv[kk][ct]);
                acc[ct] = __builtin_amdgcn_mfma_f32_16x16x32_bf16(a, b, acc[ct], 0, 0, 0);
            }
        }
        __builtin_amdgcn_s_barrier();
    }
#undef ISSUE

    #pragma unroll
    for (int ct = 0; ct < 4; ++ct) {
        int c = ct * 16 + fr_lo;
        #pragma unroll
        for (int r = 0; r < 4; ++r) {
            int row = wave * 16 + fr_hi * 4 + r;
            atomicAdd(&hpre[(size_t)(row0 + row) * HID + c], acc[ct][r]);
        }
    }
}

// ---- layer-1 aggregation: wave = 4 edge-groups x 16 lanes (4 cols each).
__global__ __launch_bounds__(256) void aggfin1_k(
        const int2* __restrict__ slots2, const int* __restrict__ ptr,
        const float* __restrict__ deg, const float* __restrict__ hpre,
        const float* __restrict__ b1, const float* __restrict__ W2,
        float* __restrict__ s_out) {
    int wave = threadIdx.x >> 6;
    int lane = threadIdx.x & 63;
    int dst  = blockIdx.x * 4 + wave;
    int g    = lane >> 4;
    int l    = lane & 15;
    int n    = min(ptr[dst], CAP);
    int base = dst * CAP;
    float dd = rsqrtf(deg[dst] + 1.0f);

    f32x4 acc = {0.f, 0.f, 0.f, 0.f};
    for (int j = g; j < n; j += 4) {
        int2 pr  = slots2[base + j];
        float wn = rsqrtf(deg[pr.x] + 1.0f) * __int_as_float(pr.y) * dd;
        f32x4 h  = *(const f32x4*)&hpre[(size_t)pr.x * HID + l * 4];
        acc += wn * h;
    }
    #pragma unroll
    for (int c = 0; c < 4; ++c) {
        acc[c] += __shfl_xor(acc[c], 16);
        acc[c] += __shfl_xor(acc[c], 32);
    }
    f32x4 hself = *(const f32x4*)&hpre[(size_t)dst * HID + l * 4];
    f32x4 bb    = *(const f32x4*)&b1[l * 4];
    f32x4 ww    = *(const f32x4*)&W2[l * 4];
    float tv = 0.f;
    #pragma unroll
    for (int c = 0; c < 4; ++c) {
        float v = fmaxf(acc[c] + dd * dd * hself[c] + bb[c], 0.f);
        tv += v * ww[c];
    }
    #pragma unroll
    for (int off = 1; off < 16; off <<= 1) tv += __shfl_xor(tv, off);
    if (lane == 0) s_out[dst] = tv;
}

// ---- layer-2 aggregation: one wave per dst, lanes parallel, wn on the fly.
__global__ __launch_bounds__(256) void agg2fin2_k(
        const int2* __restrict__ slots2, const int* __restrict__ ptr,
        const float* __restrict__ deg, const float* __restrict__ s,
        const float* __restrict__ b2, float* __restrict__ out) {
    int wave = threadIdx.x >> 6;
    int lane = threadIdx.x & 63;
    int dst  = blockIdx.x * 4 + wave;
    int n    = min(ptr[dst], CAP);
    float dd = rsqrtf(deg[dst] + 1.0f);
    float acc = 0.f;
    for (int j = lane; j < n; j += 64) {
        int2 pr = slots2[dst * CAP + j];
        acc += rsqrtf(deg[pr.x] + 1.0f) * __int_as_float(pr.y) * dd * s[pr.x];
    }
    #pragma unroll
    for (int off = 32; off > 0; off >>= 1) acc += __shfl_xor(acc, off);
    if (lane == 0) out[dst] = acc + dd * dd * s[dst] + b2[0];
}

extern "C" void kernel_launch(void* const* d_in, const int* in_sizes, int n_in,
                              void* d_out, int out_size, void* d_ws, size_t ws_size,
                              hipStream_t stream) {
    const float* x  = (const float*)d_in[0];
    const int*   ei = (const int*)d_in[1];      // int32 (harness delivers integers as int)
    const float* ew = (const float*)d_in[2];
    const float* W1 = (const float*)d_in[3];
    const float* b1 = (const float*)d_in[4];
    const float* W2 = (const float*)d_in[5];
    const float* b2 = (const float*)d_in[6];
    float* out = (float*)d_out;

    char* ws = (char*)d_ws;
    unsigned* w1t   = (unsigned*)(ws);                             // 2 MiB
    float*    hpre  = (float*)(ws + (2u << 20));                   // 4 MiB [zeroed]
    int*      ptr   = (int*)  (ws + (6u << 20));                   // 64 KiB [zeroed]
    float*    deg   = (float*)(ws + (6u << 20) + (64u << 10));     // 64 KiB [zeroed]
    float*    s     = (float*)(ws + (6u << 20) + (128u << 10));    // 64 KiB
    int2*     slots2= (int2*) (ws + (7u << 20));                   // 10.5 MiB

    // zero hpre + ptr + deg (contiguous)
    hipMemsetAsync(ws + (2u << 20), 0, (4u << 20) + (128u << 10), stream);

    pack_w1t<<<(64 * (KDIM / 2)) / 256, 256, 0, stream>>>(W1, w1t);
    gemm_deg_k<<<dim3(N_NODES / 64, 3), 256, 0, stream>>>(x, w1t, hpre, ei, ew, deg, ptr, slots2);
    aggfin1_k<<<N_NODES / 4, 256, 0, stream>>>(slots2, ptr, deg, hpre, b1, W2, s);
    agg2fin2_k<<<N_NODES / 4, 256, 0, stream>>>(slots2, ptr, deg, s, b2, out);
}

// Round 18
// 293.131 us; speedup vs baseline: 1.0953x; 1.0216x over previous
//
#include <hip/hip_runtime.h>
#include <hip/hip_bf16.h>

#define N_NODES 16384
#define KDIM    16384
#define HID     64
#define N_EDGES 524288
#define BK      64
#define CAP     80
#define PACK_BLKS 2048   /* 64 cols * 8192 k-pairs / 256 threads */
#define ZH_BLKS   1024   /* hpre 4 MiB / (256 threads * 16 B) */
#define ZP_BLKS   32     /* ptr+deg 128 KiB / (256 * 16 B) */

typedef __bf16 bf16x8 __attribute__((ext_vector_type(8)));
typedef float  f32x4  __attribute__((ext_vector_type(4)));
typedef unsigned uint32x4 __attribute__((ext_vector_type(4)));
typedef __attribute__((address_space(3))) const unsigned* lds_cptr_t;

__device__ __forceinline__ unsigned cvt_pk(float a, float b) {
    unsigned r;
    asm("v_cvt_pk_bf16_f32 %0, %1, %2" : "=v"(r) : "v"(a), "v"(b));
    return r;
}

__device__ __forceinline__ void gload16(const void* g, void* l) {
    __builtin_amdgcn_global_load_lds(
        (const __attribute__((address_space(1))) unsigned*)g,
        (__attribute__((address_space(3))) unsigned*)l,
        16, 0, 0);
}

__device__ __forceinline__ uint32x4 ds_read128(lds_cptr_t p) {
    uint32x4 r;
    asm volatile("ds_read_b128 %0, %1" : "=v"(r) : "v"(p));
    return r;
}

// ---- pack W1 -> W1t (bf16 pairs) + zero hpre/ptr/deg (memset dispatch fused)
__global__ void pack_zero_k(const float* __restrict__ W1, unsigned* __restrict__ W1t,
                            float* __restrict__ hpre, float* __restrict__ ptrdeg) {
    unsigned bx = blockIdx.x;
    if (bx < PACK_BLKS) {
        int tid = bx * 256 + threadIdx.x;       // 0..524287
        int c  = tid & 63;
        int kp = tid >> 6;                      // 0..8191
        float f0 = W1[(size_t)(2 * kp)     * HID + c];
        float f1 = W1[(size_t)(2 * kp + 1) * HID + c];
        W1t[(size_t)c * (KDIM / 2) + kp] = cvt_pk(f0, f1);
    } else if (bx < PACK_BLKS + ZH_BLKS) {
        int b = bx - PACK_BLKS;
        ((f32x4*)hpre)[b * 256 + threadIdx.x] = f32x4{0.f, 0.f, 0.f, 0.f};
    } else {
        int b = bx - (PACK_BLKS + ZH_BLKS);
        ((f32x4*)ptrdeg)[b * 256 + threadIdx.x] = f32x4{0.f, 0.f, 0.f, 0.f};
    }
}

// ---- fused: degree accumulation + (sidx, raw w) pair scatter (one edge pass)
__global__ void deg_scat_k(const int* __restrict__ ei, const float* __restrict__ w,
                           float* deg, int* ptr, int2* __restrict__ slots2) {
    int e = blockIdx.x * 256 + threadIdx.x;
    int d = ei[N_EDGES + e];
    float we = w[e];
    atomicAdd(&deg[d], we);
    int pos = atomicAdd(&ptr[d], 1);
    if (pos < CAP) slots2[d * CAP + pos] = make_int2(ei[e], __float_as_int(we));
}

// ---- hpre = x @ W1 : measured ~194 us = 5.6 TB/s (88% of achievable). Frozen.
__global__ __launch_bounds__(256, 3) void gemm1(const float* __restrict__ x,
                                                const unsigned* __restrict__ w1t,
                                                float* __restrict__ hpre) {
    __shared__ unsigned As_u[2][64 * 64];
    __shared__ unsigned Bs_u[2][64 * 32];

    const int t    = threadIdx.x;
    const int wave = t >> 6;
    const int lane = t & 63;
    const int row0 = blockIdx.x * 64;
    const int y    = blockIdx.y;
    const int k00  = y * 5504;
    const int NTb  = (y < 2) ? 86 : 84;
    const int fr_lo = lane & 15, fr_hi = lane >> 4;
    const int ar    = wave * 16 + fr_lo;

    const float* pA[4];
    #pragma unroll
    for (int i = 0; i < 4; ++i) {
        int row = (wave * 4 + i) * 4 + (lane >> 4);
        int col = ((lane & 15) ^ (row & 15)) * 4;
        pA[i] = x + (size_t)(row0 + row) * KDIM + k00 + col;
    }
    const unsigned* pB[2];
    #pragma unroll
    for (int i = 0; i < 2; ++i) {
        int c = (wave * 2 + i) * 8 + (lane >> 3);
        int s = ((lane & 7) ^ (c & 7)) * 4;
        pB[i] = w1t + (size_t)c * (KDIM / 2) + (k00 >> 1) + s;
    }

    f32x4 acc[4] = {{0.f,0.f,0.f,0.f},{0.f,0.f,0.f,0.f},{0.f,0.f,0.f,0.f},{0.f,0.f,0.f,0.f}};

#define ISSUE(buf) do {                                                          \
    _Pragma("unroll") for (int i = 0; i < 4; ++i)                                \
        gload16(pA[i], &As_u[buf][(wave * 4 + i) * 256]);                        \
    _Pragma("unroll") for (int i = 0; i < 2; ++i)                                \
        gload16(pB[i], &Bs_u[buf][(wave * 2 + i) * 256]);                        \
    _Pragma("unroll") for (int i = 0; i < 4; ++i) pA[i] += BK;                   \
    _Pragma("unroll") for (int i = 0; i < 2; ++i) pB[i] += BK / 2;               \
    } while (0)

    ISSUE(0);

    #pragma unroll 1
    for (int tt = 0; tt < NTb; ++tt) {
        const int buf = tt & 1;
        if (tt + 1 < NTb) {
            ISSUE(buf ^ 1);
            asm volatile("s_waitcnt vmcnt(6)" ::: "memory");
        } else {
            asm volatile("s_waitcnt vmcnt(0)" ::: "memory");
        }
        __builtin_amdgcn_s_barrier();

        const lds_cptr_t Ab = (lds_cptr_t)&As_u[buf][0];
        const lds_cptr_t Bb = (lds_cptr_t)&Bs_u[buf][0];
        uint32x4 av0[2], av1[2], bv[2][4];
        #pragma unroll
        for (int kk = 0; kk < 2; ++kk) {
            int s0 = (kk * 8 + fr_hi * 2) ^ fr_lo;
            av0[kk] = ds_read128(Ab + ar * 64 + s0 * 4);
            av1[kk] = ds_read128(Ab + ar * 64 + (s0 ^ 1) * 4);
            #pragma unroll
            for (int ct = 0; ct < 4; ++ct) {
                int bc = ct * 16 + fr_lo;
                bv[kk][ct] = ds_read128(Bb + bc * 32 + (((kk * 4 + fr_hi) ^ (fr_lo & 7)) << 2));
            }
        }
        asm volatile("s_waitcnt lgkmcnt(0)" ::: "memory");
        __builtin_amdgcn_sched_barrier(0);

        #pragma unroll
        for (int kk = 0; kk < 2; ++kk) {
            f32x4 v0 = __builtin_bit_cast(f32x4, av0[kk]);
            f32x4 v1 = __builtin_bit_cast(f32x4, av1[kk]);
            uint32x4 au = { cvt_pk(v0[0], v0[1]), cvt_pk(v0[2], v0[3]),
                            cvt_pk(v1[0], v1[1]), cvt_pk(v1[2], v1[3]) };
            bf16x8 a = __builtin_bit_cast(bf16x8, au);
            #pragma unroll
            for (int ct = 0; ct < 4; ++ct) {
                bf16x8 b = __builtin_bit_cast(bf16x8, bv[kk][ct]);
                acc[ct] = __builtin_amdgcn_mfma_f32_16x16x32_bf16(a, b, acc[ct], 0, 0, 0);
            }
        }
        __builtin_amdgcn_s_barrier();
    }
#undef ISSUE

    #pragma unroll
    for (int ct = 0; ct < 4; ++ct) {
        int c = ct * 16 + fr_lo;
        #pragma unroll
        for (int r = 0; r < 4; ++r) {
            int row = wave * 16 + fr_hi * 4 + r;
            atomicAdd(&hpre[(size_t)(row0 + row) * HID + c], acc[ct][r]);
        }
    }
}

// ---- layer-1 aggregation: wave = 4 edge-groups x 16 lanes (4 cols each).
__global__ __launch_bounds__(256) void aggfin1_k(
        const int2* __restrict__ slots2, const int* __restrict__ ptr,
        const float* __restrict__ deg, const float* __restrict__ hpre,
        const float* __restrict__ b1, const float* __restrict__ W2,
        float* __restrict__ s_out) {
    int wave = threadIdx.x >> 6;
    int lane = threadIdx.x & 63;
    int dst  = blockIdx.x * 4 + wave;
    int g    = lane >> 4;
    int l    = lane & 15;
    int n    = min(ptr[dst], CAP);
    int base = dst * CAP;
    float dd = rsqrtf(deg[dst] + 1.0f);

    f32x4 acc = {0.f, 0.f, 0.f, 0.f};
    for (int j = g; j < n; j += 4) {
        int2 pr  = slots2[base + j];
        float wn = rsqrtf(deg[pr.x] + 1.0f) * __int_as_float(pr.y) * dd;
        f32x4 h  = *(const f32x4*)&hpre[(size_t)pr.x * HID + l * 4];
        acc += wn * h;
    }
    #pragma unroll
    for (int c = 0; c < 4; ++c) {
        acc[c] += __shfl_xor(acc[c], 16);
        acc[c] += __shfl_xor(acc[c], 32);
    }
    f32x4 hself = *(const f32x4*)&hpre[(size_t)dst * HID + l * 4];
    f32x4 bb    = *(const f32x4*)&b1[l * 4];
    f32x4 ww    = *(const f32x4*)&W2[l * 4];
    float tv = 0.f;
    #pragma unroll
    for (int c = 0; c < 4; ++c) {
        float v = fmaxf(acc[c] + dd * dd * hself[c] + bb[c], 0.f);
        tv += v * ww[c];
    }
    #pragma unroll
    for (int off = 1; off < 16; off <<= 1) tv += __shfl_xor(tv, off);
    if (lane == 0) s_out[dst] = tv;
}

// ---- layer-2 aggregation: one wave per dst, lanes parallel, wn on the fly.
__global__ __launch_bounds__(256) void agg2fin2_k(
        const int2* __restrict__ slots2, const int* __restrict__ ptr,
        const float* __restrict__ deg, const float* __restrict__ s,
        const float* __restrict__ b2, float* __restrict__ out) {
    int wave = threadIdx.x >> 6;
    int lane = threadIdx.x & 63;
    int dst  = blockIdx.x * 4 + wave;
    int n    = min(ptr[dst], CAP);
    float dd = rsqrtf(deg[dst] + 1.0f);
    float acc = 0.f;
    for (int j = lane; j < n; j += 64) {
        int2 pr = slots2[dst * CAP + j];
        acc += rsqrtf(deg[pr.x] + 1.0f) * __int_as_float(pr.y) * dd * s[pr.x];
    }
    #pragma unroll
    for (int off = 32; off > 0; off >>= 1) acc += __shfl_xor(acc, off);
    if (lane == 0) out[dst] = acc + dd * dd * s[dst] + b2[0];
}

extern "C" void kernel_launch(void* const* d_in, const int* in_sizes, int n_in,
                              void* d_out, int out_size, void* d_ws, size_t ws_size,
                              hipStream_t stream) {
    const float* x  = (const float*)d_in[0];
    const int*   ei = (const int*)d_in[1];      // int32 (harness delivers integers as int)
    const float* ew = (const float*)d_in[2];
    const float* W1 = (const float*)d_in[3];
    const float* b1 = (const float*)d_in[4];
    const float* W2 = (const float*)d_in[5];
    const float* b2 = (const float*)d_in[6];
    float* out = (float*)d_out;

    char* ws = (char*)d_ws;
    unsigned* w1t   = (unsigned*)(ws);                             // 2 MiB
    float*    hpre  = (float*)(ws + (2u << 20));                   // 4 MiB [zeroed]
    int*      ptr   = (int*)  (ws + (6u << 20));                   // 64 KiB [zeroed]
    float*    deg   = (float*)(ws + (6u << 20) + (64u << 10));     // 64 KiB [zeroed]
    float*    s     = (float*)(ws + (6u << 20) + (128u << 10));    // 64 KiB
    int2*     slots2= (int2*) (ws + (7u << 20));                   // 10.5 MiB

    pack_zero_k<<<PACK_BLKS + ZH_BLKS + ZP_BLKS, 256, 0, stream>>>(W1, w1t, hpre, (float*)ptr);
    deg_scat_k<<<N_EDGES / 256, 256, 0, stream>>>(ei, ew, deg, ptr, slots2);
    gemm1<<<dim3(N_NODES / 64, 3), 256, 0, stream>>>(x, w1t, hpre);
    aggfin1_k<<<N_NODES / 4, 256, 0, stream>>>(slots2, ptr, deg, hpre, b1, W2, s);
    agg2fin2_k<<<N_NODES / 4, 256, 0, stream>>>(slots2, ptr, deg, s, b2, out);
}